// Round 8
// baseline (163.597 us; speedup 1.0000x reference)
//
#include <hip/hip_runtime.h>
#include <hip/hip_bf16.h>
#include <math.h>

// ProxyGML: B=1024, DIM=512, C=1000, N=8
#define PB   1024
#define PDIM 512
#define PC   1000
#define PN   8
#define PCN  8000
#define PTOPK 400
#define NONPOS_K 392

typedef __bf16 bf16x8 __attribute__((ext_vector_type(8)));
typedef __bf16 bf16x4 __attribute__((ext_vector_type(4)));
typedef float  f32x16 __attribute__((ext_vector_type(16)));

__device__ static inline void async_load16(const __bf16* g, __bf16* l) {
    __builtin_amdgcn_global_load_lds(
        (const __attribute__((address_space(1))) void*)g,
        (__attribute__((address_space(3))) void*)l,
        16, 0, 0);
}

// ----------------------------------------------------------------- pre ----
// b<512: x->bf16. 512..767: P column-ssq partials. 768+: zero esum/diag and
// ccls pad rows (classes 1000..1023).
__global__ __launch_bounds__(256) void k_pre(const float* __restrict__ x,
                                             const float* __restrict__ P,
                                             __bf16* __restrict__ xb,
                                             float* __restrict__ ssqp,
                                             float* __restrict__ esd,
                                             float* __restrict__ padf,
                                             float* __restrict__ acc) {
    int b = blockIdx.x, tid = threadIdx.x;
    if (b == 0 && tid < 8) acc[tid] = 0.f;
    if (b < 512) {
        int i = b * 256 + tid;
        float4 v = ((const float4*)x)[i];
        bf16x4 o;
        o[0] = (__bf16)v.x; o[1] = (__bf16)v.y; o[2] = (__bf16)v.z; o[3] = (__bf16)v.w;
        ((bf16x4*)xb)[i] = o;
    } else if (b < 768) {
        int idx = b - 512;              // 0..255
        int slice = idx & 7, jb = idx >> 3;
        int j = jb * 256 + tid;
        if (j < PCN) {
            const float* p = P + (size_t)(slice * 64) * PCN + j;
            float ss = 0.f;
#pragma unroll 8
            for (int r = 0; r < 64; ++r) {
                float v = p[(size_t)r * PCN];
                ss = fmaf(v, v, ss);
            }
            ssqp[slice * PCN + j] = ss;
        }
    } else {
        int i = (b - 768) * 256 + tid;  // 0..22271
        if (i < 16000) esd[i] = 0.f;
        else if (i < 16000 + 6144) padf[i - 16000] = 0.f;  // 24x512 bf16 pad
    }
}

// ---------------- P (512x8000) -> Pt bf16 (8000x512) + fused ccls ---------
__global__ __launch_bounds__(256) void k_tpose(const float* __restrict__ P,
                                               const float* __restrict__ ssqp,
                                               __bf16* __restrict__ Pt,
                                               __bf16* __restrict__ ccls) {
    __shared__ float t[64][65];
    __shared__ float sinv[64];
    int tid = threadIdx.x;
    int tx = tid & 63, ty = tid >> 6;
    int j0 = blockIdx.x * 64, d0 = blockIdx.y * 64;
    if (tid < 64) {
        float sq = 0.f;
#pragma unroll
        for (int p2 = 0; p2 < 8; ++p2) sq += ssqp[p2 * PCN + j0 + tid];
        sinv[tid] = 1.0f / fmaxf(sqrtf(sq), 1e-12f);
    }
#pragma unroll
    for (int r = 0; r < 16; ++r) {
        int d = d0 + ty * 16 + r;
        t[ty * 16 + r][tx] = P[(size_t)d * PCN + j0 + tx];
    }
    __syncthreads();
    float cs0 = 0.f, cs1 = 0.f;
#pragma unroll
    for (int r = 0; r < 16; ++r) {
        int jl = ty * 16 + r;
        float val = t[tx][jl] * sinv[jl];
        Pt[(size_t)(j0 + jl) * PDIM + d0 + tx] = (__bf16)val;
        if (r < 8) cs0 += val; else cs1 += val;
    }
    int c0 = (j0 >> 3) + ty * 2;           // 16 j's = 2 whole classes
    ccls[(size_t)c0 * PDIM + d0 + tx] = (__bf16)cs0;
    ccls[(size_t)(c0 + 1) * PDIM + d0 + tx] = (__bf16)cs1;
}

// ------------------------------------------------- GEMM core (macros) -----
#define GEMM_STAGE(A, Bt, Ma, Nb, m0, n0, buf, k0) {                          \
    _Pragma("unroll")                                                         \
    for (int pass = 0; pass < 2; ++pass) {                                    \
        int cc_ = pass * 256 + w * 64 + lane;                                 \
        int arow = (m0) + (cc_ >> 2); if (arow > (Ma) - 1) arow = (Ma) - 1;   \
        async_load16((A) + (size_t)arow * PDIM + (k0) + (cc_ & 3) * 8,        \
                     &As[buf][cc_ * 8]);                                      \
        int brow = (n0) + (cc_ >> 2); if (brow > (Nb) - 1) brow = (Nb) - 1;   \
        async_load16((Bt) + (size_t)brow * PDIM + (k0) + (cc_ & 3) * 8,       \
                     &Bs[buf][cc_ * 8]);                                      \
    } }

// 32x32x16 mfma: A row = lane&31, k = 8*(lane>>5)+e; 2x2 tiles/wave (64x64)
#define GEMM_CORE(A, Bt, Ma, Nb, m0, n0)                                      \
    GEMM_STAGE(A, Bt, Ma, Nb, m0, n0, 0, 0)                                   \
    for (int it = 0; it < 16; ++it) {                                         \
        int cur = it & 1;                                                     \
        __syncthreads();                                                      \
        if (it < 15) GEMM_STAGE(A, Bt, Ma, Nb, m0, n0, cur ^ 1, (it + 1) * 32)\
        _Pragma("unroll")                                                     \
        for (int h = 0; h < 2; ++h) {                                         \
            bf16x8 av[2], bv[2];                                              \
            _Pragma("unroll")                                                 \
            for (int t2 = 0; t2 < 2; ++t2) {                                  \
                av[t2] = *(const bf16x8*)&As[cur][(wr * 64 + t2 * 32 + l31) * 32 + h * 16 + half8]; \
                bv[t2] = *(const bf16x8*)&Bs[cur][(wc * 64 + t2 * 32 + l31) * 32 + h * 16 + half8]; \
            }                                                                 \
            _Pragma("unroll")                                                 \
            for (int ti = 0; ti < 2; ++ti)                                    \
                _Pragma("unroll")                                             \
                for (int tj = 0; tj < 2; ++tj)                                \
                    acc[ti][tj] = __builtin_amdgcn_mfma_f32_32x32x16_bf16(    \
                        av[ti], bv[tj], acc[ti][tj], 0, 0, 0);                \
        }                                                                     \
    }

// ---------------- merged GEMM1 (sim bf16) + GEMM2r (esum/diag) ------------
__global__ __launch_bounds__(256) void k_gemms(const __bf16* __restrict__ xb,
                                               const __bf16* __restrict__ Pt,
                                               const __bf16* __restrict__ ccls,
                                               __bf16* __restrict__ simb,
                                               float* __restrict__ esum,
                                               float* __restrict__ diag) {
    __shared__ __bf16 As[2][128 * 32];
    __shared__ __bf16 Bs[2][128 * 32];
    int tid = threadIdx.x;
    int w = tid >> 6, lane = tid & 63;
    int wr = w >> 1, wc = w & 1;
    int l31 = lane & 31, half8 = (lane >> 5) * 8;
    f32x16 acc[2][2] = {};
    int id = blockIdx.x;
    if (id < 504) {
        int n0 = (id % 63) * 128, m0 = (id / 63) * 128;
        GEMM_CORE(xb, Pt, PB, PCN, m0, n0)
#pragma unroll
        for (int ti = 0; ti < 2; ++ti)
#pragma unroll
            for (int tj = 0; tj < 2; ++tj) {
                int cc = n0 + wc * 64 + tj * 32 + l31;
                if (cc < PCN) {
#pragma unroll
                    for (int reg = 0; reg < 16; ++reg) {
                        int rr = m0 + wr * 64 + ti * 32
                               + (reg & 3) + 8 * (reg >> 2) + 4 * (lane >> 5);
                        simb[(size_t)rr * PCN + cc] = (__bf16)acc[ti][tj][reg];
                    }
                }
            }
    } else {
        int id2 = id - 504;
        int n0 = (id2 % 8) * 128, m0 = (id2 / 8) * 128;
        GEMM_CORE(Pt, ccls, PCN, PB, m0, n0)
#pragma unroll
        for (int ti = 0; ti < 2; ++ti) {
            float ps[16] = {};
#pragma unroll
            for (int tj = 0; tj < 2; ++tj) {
                int cc = n0 + wc * 64 + tj * 32 + l31;
                bool cvalid = (cc < PC);
#pragma unroll
                for (int reg = 0; reg < 16; ++reg) {
                    float v = acc[ti][tj][reg];
                    int rr = m0 + wr * 64 + ti * 32
                           + (reg & 3) + 8 * (reg >> 2) + 4 * (lane >> 5);
                    if (cvalid) {
                        ps[reg] += expf(v);
                        if (rr < PCN && cc == (rr >> 3)) diag[rr] = v;
                    }
                }
            }
#pragma unroll
            for (int reg = 0; reg < 16; ++reg) {
#pragma unroll
                for (int off = 1; off < 32; off <<= 1)
                    ps[reg] += __shfl_xor(ps[reg], off, 64);
                if (l31 == 0) {
                    int rr = m0 + wr * 64 + ti * 32
                           + (reg & 3) + 8 * (reg >> 2) + 4 * (lane >> 5);
                    if (rr < PCN) atomicAdd(&esum[rr], ps[reg]);
                }
            }
        }
    }
}

// ------------------------------------------------------------- row loss ---
// Exact top-k threshold on bf16 codes: 2-pass 256-bin histogram over the
// monotone 16-bit key (hi byte, then lo byte). No candidates, no min/max.
// Ties at tau resolved by index order via parallel prefix scan.
__global__ __launch_bounds__(256) void k_rowloss(const __bf16* __restrict__ sim,
                                                 const int* __restrict__ target,
                                                 float* __restrict__ acc) {
    __shared__ unsigned hist[4][256];
    __shared__ unsigned wtot[4];
    __shared__ float redf[4];
    __shared__ int s_hb, s_A1, s_lb, s_A2, s_eq;
    __shared__ float s_et;

    int b = blockIdx.x, tid = threadIdx.x;
    int lane = tid & 63, wv = tid >> 6;
    const uint4* row16 = (const uint4*)(sim + (size_t)b * PCN);
    int targ = target[b];

#pragma unroll
    for (int k = 0; k < 4; ++k) hist[k][tid] = 0u;

    // load 4 classes (8 bf16 = one uint4 each) as raw codes
    uint4 kv[4];
#pragma unroll
    for (int k = 0; k < 4; ++k) {
        int c = tid + 256 * k;
        kv[k] = (c < PC) ? row16[c] : make_uint4(0u, 0u, 0u, 0u);
    }
    __syncthreads();

    // key extraction: monotone map of bf16 code
#define KEYOF(k, n) ({                                                        \
    unsigned u_ = ((const unsigned*)&kv[k])[(n) >> 1];                        \
    unsigned c_ = ((n) & 1) ? (u_ >> 16) : (u_ & 0xFFFFu);                    \
    (c_ & 0x8000u) ? (c_ ^ 0xFFFFu) : (c_ | 0x8000u); })
#define VALOF(k, n) ({                                                        \
    unsigned u_ = ((const unsigned*)&kv[k])[(n) >> 1];                        \
    unsigned c_ = ((n) & 1) ? (u_ & 0xFFFF0000u) : (u_ << 16);                \
    __uint_as_float(c_); })

    // pass 1: per-wave histogram of key high byte
#pragma unroll
    for (int k = 0; k < 4; ++k) {
        int c = tid + 256 * k;
        if (c < PC && c != targ) {
#pragma unroll
            for (int n = 0; n < 8; ++n)
                atomicAdd(&hist[wv][KEYOF(k, n) >> 8], 1u);
        }
    }
    __syncthreads();

    // suffix scan over 256 bins (1 bin/thread)
    unsigned h1 = hist[0][tid] + hist[1][tid] + hist[2][tid] + hist[3][tid];
    {
        unsigned inc = h1;
#pragma unroll
        for (int step = 1; step < 64; step <<= 1) {
            unsigned u = __shfl_down(inc, step, 64);
            if (lane + step < 64) inc += u;
        }
        if (lane == 0) wtot[wv] = inc;
        __syncthreads();
        unsigned tail = 0;
#pragma unroll
        for (int w2 = 0; w2 < 4; ++w2) if (w2 > wv) tail += wtot[w2];
        unsigned sfx = inc + tail, nxt = sfx - h1;
        if (sfx >= NONPOS_K && nxt < NONPOS_K) { s_hb = tid; s_A1 = (int)nxt; }
    }
    __syncthreads();
    int hb = s_hb, A1 = s_A1;
    hist[0][tid] = 0u;                       // reuse for pass 2
    __syncthreads();

    // pass 2: low byte within the hb group
#pragma unroll
    for (int k = 0; k < 4; ++k) {
        int c = tid + 256 * k;
        if (c < PC && c != targ) {
#pragma unroll
            for (int n = 0; n < 8; ++n) {
                unsigned key = KEYOF(k, n);
                if ((int)(key >> 8) == hb) atomicAdd(&hist[0][key & 255u], 1u);
            }
        }
    }
    __syncthreads();
    unsigned h2 = hist[0][tid];
    {
        int rank2 = NONPOS_K - A1;
        unsigned inc = h2;
#pragma unroll
        for (int step = 1; step < 64; step <<= 1) {
            unsigned u = __shfl_down(inc, step, 64);
            if (lane + step < 64) inc += u;
        }
        __syncthreads();                     // wtot reuse
        if (lane == 0) wtot[wv] = inc;
        __syncthreads();
        unsigned tail = 0;
#pragma unroll
        for (int w2 = 0; w2 < 4; ++w2) if (w2 > wv) tail += wtot[w2];
        unsigned sfx = inc + tail, nxt = sfx - h2;
        if (sfx >= (unsigned)rank2 && nxt < (unsigned)rank2) {
            s_lb = tid; s_A2 = (int)nxt; s_eq = (int)h2;
        }
    }
    __syncthreads();
    unsigned tkey = ((unsigned)hb << 8) | (unsigned)s_lb;
    int cgt = A1 + s_A2, ceq = s_eq;
    int rem = NONPOS_K - cgt;                // ties to include, by index order
    bool all_eq = (rem >= ceq);

    // parallel tie offsets in index order
    int offs[4] = {0, 0, 0, 0};
    if (!all_eq) {
        unsigned chunk_base = 0;
#pragma unroll
        for (int k = 0; k < 4; ++k) {
            int c = tid + 256 * k;
            unsigned tn = 0;
            if (c < PC && c != targ) {
#pragma unroll
                for (int n = 0; n < 8; ++n) tn += (KEYOF(k, n) == tkey) ? 1u : 0u;
            }
            unsigned inc = tn;
#pragma unroll
            for (int step = 1; step < 64; step <<= 1) {
                unsigned u = __shfl_up(inc, step, 64);
                if (lane >= step) inc += u;
            }
            __syncthreads();
            if (lane == 63) wtot[wv] = inc;
            __syncthreads();
            unsigned base = 0;
#pragma unroll
            for (int w2 = 0; w2 < 4; ++w2) if (w2 < wv) base += wtot[w2];
            offs[k] = (int)(chunk_base + base + inc - tn);
            chunk_base += wtot[0] + wtot[1] + wtot[2] + wtot[3];
        }
    }

    // logits -> exp -> loss
    float psum = 0.f;
#pragma unroll
    for (int k = 0; k < 4; ++k) {
        int c = tid + 256 * k;
        if (c >= PC) continue;
        float lg = 0.f;
        if (c == targ) {
#pragma unroll
            for (int n = 0; n < 8; ++n) lg += VALOF(k, n);
        } else {
#pragma unroll
            for (int n = 0; n < 8; ++n) {
                unsigned key = KEYOF(k, n);
                bool sel = key > tkey;
                if (!sel && key == tkey) {
                    if (all_eq) sel = true;
                    else { sel = (offs[k] < rem); offs[k]++; }
                }
                if (sel) lg += VALOF(k, n);
            }
        }
        float e = (lg != 0.0f) ? expf(lg) : 0.0f;
        psum += e;
        if (c == targ) s_et = e;
    }
    for (int off = 32; off; off >>= 1) psum += __shfl_down(psum, off, 64);
    if (lane == 0) redf[wv] = psum;
    __syncthreads();
    if (tid == 0) {
        float denom = 1e-8f + redf[0] + redf[1] + redf[2] + redf[3];
        atomicAdd(acc, -logf(s_et / denom + 1e-20f));
    }
#undef KEYOF
#undef VALOF
}

// --------------------------------------------------------------- final ----
__global__ __launch_bounds__(256) void k_final(const float* __restrict__ esum,
                                               const float* __restrict__ diag,
                                               const float* __restrict__ acc,
                                               float* __restrict__ out) {
    __shared__ float redf[4];
    int tid = threadIdx.x, lane = tid & 63, wv = tid >> 6;
    float s = 0.f;
    for (int j = tid; j < PCN; j += 256)
        s += logf(esum[j]) - diag[j];
    for (int off = 32; off; off >>= 1) s += __shfl_down(s, off, 64);
    if (lane == 0) redf[wv] = s;
    __syncthreads();
    if (tid == 0) {
        float rg = (redf[0] + redf[1] + redf[2] + redf[3]) * (1.0f / PCN);
        float lc = acc[0] * (1.0f / PB);
        out[0] = lc + 0.3f * rg;
        out[1] = lc;
    }
}

// ---------------------------------------------------------------------------
extern "C" void kernel_launch(void* const* d_in, const int* in_sizes, int n_in,
                              void* d_out, int out_size, void* d_ws, size_t ws_size,
                              hipStream_t stream) {
    const float* x       = (const float*)d_in[0];   // (1024, 512)
    const float* proxies = (const float*)d_in[1];   // (512, 8000)
    const int*   target  = (const int*)d_in[2];     // (1024,)
    float* out = (float*)d_out;
    float* ws  = (float*)d_ws;

    // workspace layout (float offsets)
    float*  acc   = ws;                       // [0]=loss
    float*  ssqp  = ws + 64;                  // 8 x 8000
    float*  esum  = ws + 64064;               // 8000
    float*  diag  = ws + 72064;               // 8000
    __bf16* xb    = (__bf16*)(ws + 80064);    // 1024x512 bf16
    __bf16* cclsb = (__bf16*)(ws + 342208);   // 1024x512 bf16 (24 pad rows)
    __bf16* Pt    = (__bf16*)(ws + 604352);   // 8000x512 bf16
    __bf16* simb  = (__bf16*)(ws + 2652352);  // 1024x8000 bf16
    // total 6,748,352 floats = 27.0 MiB

    float* padf = (float*)cclsb + 256000;     // ccls rows 1000..1023 as f32

    k_pre<<<856, 256, 0, stream>>>(x, proxies, xb, ssqp, esum, padf, acc);
    k_tpose<<<dim3(125, 8), 256, 0, stream>>>(proxies, ssqp, Pt, cclsb);

    k_gemms<<<1008, 256, 0, stream>>>(xb, Pt, cclsb, simb, esum, diag);

    k_rowloss<<<PB, 256, 0, stream>>>(simb, target, acc);
    k_final<<<1, 256, 0, stream>>>(esum, diag, acc, out);
}

// Round 10
// 152.887 us; speedup vs baseline: 1.0701x; 1.0701x over previous
//
#include <hip/hip_runtime.h>
#include <hip/hip_bf16.h>
#include <math.h>

// ProxyGML: B=1024, DIM=512, C=1000, N=8
#define PB   1024
#define PDIM 512
#define PC   1000
#define PN   8
#define PCN  8000
#define PTOPK 400
#define NONPOS_K 392
#define NBIN 1024
#define CANDMAX 1024

typedef __bf16 bf16x8 __attribute__((ext_vector_type(8)));
typedef __bf16 bf16x4 __attribute__((ext_vector_type(4)));
typedef float  f32x4  __attribute__((ext_vector_type(4)));

__device__ static inline void async_load16(const __bf16* g, __bf16* l) {
    __builtin_amdgcn_global_load_lds(
        (const __attribute__((address_space(1))) void*)g,
        (__attribute__((address_space(3))) void*)l,
        16, 0, 0);
}

// ----------------------------------------------------------------- pre ----
// b<512: x->bf16. 512+: zero esum/diag (16000 f32) + ccls pad rows.
__global__ __launch_bounds__(256) void k_pre(const float* __restrict__ x,
                                             __bf16* __restrict__ xb,
                                             float* __restrict__ esd,
                                             float* __restrict__ padf,
                                             float* __restrict__ acc) {
    int b = blockIdx.x, tid = threadIdx.x;
    if (b == 0 && tid < 8) acc[tid] = 0.f;
    if (b < 512) {
        int i = b * 256 + tid;
        float4 v = ((const float4*)x)[i];
        bf16x4 o;
        o[0] = (__bf16)v.x; o[1] = (__bf16)v.y; o[2] = (__bf16)v.z; o[3] = (__bf16)v.w;
        ((bf16x4*)xb)[i] = o;
    } else {
        int i = (b - 512) * 256 + tid;  // 0..22527
        if (i < 16000) esd[i] = 0.f;
        else if (i < 16000 + 6144) padf[i - 16000] = 0.f;  // 24x512 bf16 pad
    }
}

// ---- P (512x8000) -> Pt bf16 (8000x512) + ccls, ssq fused (full strip) ---
// 125 blocks; block owns 64 j-columns (8 whole classes) across all 512 d.
// Phase 1: coalesced strip read -> column ssq. Phase 2: re-read (L2-hot)
// through 64x65 transpose tile, scale by sinv, emit Pt + ccls.
__global__ __launch_bounds__(256) void k_tpose(const float* __restrict__ P,
                                               __bf16* __restrict__ Pt,
                                               __bf16* __restrict__ ccls) {
    __shared__ float t[64][65];
    __shared__ float sq4[4][64];
    __shared__ float sinv[64];
    int tid = threadIdx.x;
    int lane = tid & 63, w = tid >> 6;
    int j0 = blockIdx.x * 64;

    // phase 1: ssq (thread handles column j=lane, rows d = w + 4k)
    float ss = 0.f;
#pragma unroll 8
    for (int k = 0; k < 128; ++k) {
        float v = P[(size_t)(w + 4 * k) * PCN + j0 + lane];
        ss = fmaf(v, v, ss);
    }
    sq4[w][lane] = ss;
    __syncthreads();
    if (tid < 64) {
        float s = sq4[0][tid] + sq4[1][tid] + sq4[2][tid] + sq4[3][tid];
        sinv[tid] = 1.0f / fmaxf(sqrtf(s), 1e-12f);
    }
    __syncthreads();

    // phase 2: transpose 8 chunks of 64 d
    int tx = lane, ty = w;
    for (int d0 = 0; d0 < PDIM; d0 += 64) {
#pragma unroll
        for (int r = 0; r < 16; ++r) {
            int d = d0 + ty * 16 + r;
            t[ty * 16 + r][tx] = P[(size_t)d * PCN + j0 + tx];
        }
        __syncthreads();
        float cs0 = 0.f, cs1 = 0.f;
#pragma unroll
        for (int r = 0; r < 16; ++r) {
            int jl = ty * 16 + r;
            float val = t[tx][jl] * sinv[jl];
            Pt[(size_t)(j0 + jl) * PDIM + d0 + tx] = (__bf16)val;
            if (r < 8) cs0 += val; else cs1 += val;
        }
        int c0 = (j0 >> 3) + ty * 2;       // 16 j's = 2 whole classes
        ccls[(size_t)c0 * PDIM + d0 + tx] = (__bf16)cs0;
        ccls[(size_t)(c0 + 1) * PDIM + d0 + tx] = (__bf16)cs1;
        __syncthreads();
    }
}

// ------------------------------------------------- GEMM core (macros) -----
#define GEMM_STAGE(A, Bt, Ma, Nb, m0, n0, buf, k0) {                          \
    _Pragma("unroll")                                                         \
    for (int pass = 0; pass < 2; ++pass) {                                    \
        int cc_ = pass * 256 + w * 64 + lane;                                 \
        int arow = (m0) + (cc_ >> 2); if (arow > (Ma) - 1) arow = (Ma) - 1;   \
        async_load16((A) + (size_t)arow * PDIM + (k0) + (cc_ & 3) * 8,        \
                     &As[buf][cc_ * 8]);                                      \
        int brow = (n0) + (cc_ >> 2); if (brow > (Nb) - 1) brow = (Nb) - 1;   \
        async_load16((Bt) + (size_t)brow * PDIM + (k0) + (cc_ & 3) * 8,       \
                     &Bs[buf][cc_ * 8]);                                      \
    } }

#define GEMM_CORE(A, Bt, Ma, Nb, m0, n0)                                      \
    GEMM_STAGE(A, Bt, Ma, Nb, m0, n0, 0, 0)                                   \
    for (int it = 0; it < 16; ++it) {                                         \
        int cur = it & 1;                                                     \
        __syncthreads();                                                      \
        if (it < 15) GEMM_STAGE(A, Bt, Ma, Nb, m0, n0, cur ^ 1, (it + 1) * 32)\
        bf16x8 av[4], bv[4];                                                  \
        _Pragma("unroll")                                                     \
        for (int i = 0; i < 4; ++i) {                                         \
            av[i] = *(const bf16x8*)&As[cur][(wr * 64 + i * 16 + l15) * 32 + quad * 8]; \
            bv[i] = *(const bf16x8*)&Bs[cur][(wc * 64 + i * 16 + l15) * 32 + quad * 8]; \
        }                                                                     \
        _Pragma("unroll")                                                     \
        for (int i = 0; i < 4; ++i)                                           \
            _Pragma("unroll")                                                 \
            for (int j = 0; j < 4; ++j)                                       \
                acc[i][j] = __builtin_amdgcn_mfma_f32_16x16x32_bf16(          \
                    av[i], bv[j], acc[i][j], 0, 0, 0);                        \
    }

// ---------------- merged GEMM1 (sim bf16) + GEMM2r (esum/diag) ------------
__global__ __launch_bounds__(256) void k_gemms(const __bf16* __restrict__ xb,
                                               const __bf16* __restrict__ Pt,
                                               const __bf16* __restrict__ ccls,
                                               __bf16* __restrict__ simb,
                                               float* __restrict__ esum,
                                               float* __restrict__ diag) {
    __shared__ __bf16 As[2][128 * 32];
    __shared__ __bf16 Bs[2][128 * 32];
    int tid = threadIdx.x;
    int w = tid >> 6, lane = tid & 63;
    int wr = w >> 1, wc = w & 1;
    int quad = lane >> 4, l15 = lane & 15;
    f32x4 acc[4][4] = {};
    int id = blockIdx.x;
    if (id < 504) {
        int n0 = (id % 63) * 128, m0 = (id / 63) * 128;
        GEMM_CORE(xb, Pt, PB, PCN, m0, n0)
#pragma unroll
        for (int i = 0; i < 4; ++i) {
            int r0 = m0 + wr * 64 + i * 16 + quad * 4;
#pragma unroll
            for (int j = 0; j < 4; ++j) {
                int cc = n0 + wc * 64 + j * 16 + l15;
                if (cc < PCN) {
#pragma unroll
                    for (int r = 0; r < 4; ++r)
                        simb[(size_t)(r0 + r) * PCN + cc] = (__bf16)acc[i][j][r];
                }
            }
        }
    } else {
        int id2 = id - 504;
        int n0 = (id2 % 8) * 128, m0 = (id2 / 8) * 128;
        GEMM_CORE(Pt, ccls, PCN, PB, m0, n0)
#pragma unroll
        for (int i = 0; i < 4; ++i) {
            int r0 = m0 + wr * 64 + i * 16 + quad * 4;
            float psum[4] = {0.f, 0.f, 0.f, 0.f};
#pragma unroll
            for (int j = 0; j < 4; ++j) {
                int cc = n0 + wc * 64 + j * 16 + l15;
                bool cvalid = (cc < PC);
#pragma unroll
                for (int r = 0; r < 4; ++r) {
                    float v = acc[i][j][r];
                    psum[r] += cvalid ? expf(v) : 0.f;
                    int rr = r0 + r;
                    if (cvalid && rr < PCN && cc == (rr >> 3)) diag[rr] = v;
                }
            }
#pragma unroll
            for (int off = 1; off < 16; off <<= 1)
#pragma unroll
                for (int r = 0; r < 4; ++r)
                    psum[r] += __shfl_xor(psum[r], off, 64);
            if (l15 == 0) {
#pragma unroll
                for (int r = 0; r < 4; ++r) {
                    int rr = r0 + r;
                    if (rr < PCN) atomicAdd(&esum[rr], psum[r]);
                }
            }
        }
    }
}

// ------------------------------------------------------------- row loss ---
// Register-resident bf16 row; 1024-bin histogram select for tau; ties
// resolved by index order via parallel class-order prefix scan.
__global__ __launch_bounds__(256) void k_rowloss(const __bf16* __restrict__ sim,
                                                 const int* __restrict__ target,
                                                 float* __restrict__ acc) {
    __shared__ unsigned hist[NBIN];
    __shared__ float redf[8];
    __shared__ unsigned wtot[4];
    __shared__ float cand[CANDMAX];
    __shared__ unsigned candn;
    __shared__ int s_bin, s_A;
    __shared__ float s_tau;
    __shared__ int s_gt, s_eq;
    __shared__ float s_et;

    int b = blockIdx.x, tid = threadIdx.x;
    int lane = tid & 63, wv = tid >> 6;
    const bf16x8* row8 = (const bf16x8*)(sim + (size_t)b * PCN);
    int targ = target[b];

#pragma unroll
    for (int k = 0; k < 4; ++k) hist[tid + 256 * k] = 0u;
    if (tid == 0) candn = 0u;

    float pv[4][8];
    float lmn = INFINITY, lmx = -INFINITY;
#pragma unroll
    for (int k = 0; k < 4; ++k) {
        int c = tid + 256 * k;
        if (c < PC) {
            bf16x8 vv = row8[c];
#pragma unroll
            for (int n = 0; n < 8; ++n) pv[k][n] = (float)vv[n];
            if (c != targ) {
#pragma unroll
                for (int n = 0; n < 8; ++n) {
                    lmn = fminf(lmn, pv[k][n]);
                    lmx = fmaxf(lmx, pv[k][n]);
                }
            }
        } else {
#pragma unroll
            for (int n = 0; n < 8; ++n) pv[k][n] = 0.f;
        }
    }
    for (int off = 32; off; off >>= 1) {
        lmn = fminf(lmn, __shfl_down(lmn, off, 64));
        lmx = fmaxf(lmx, __shfl_down(lmx, off, 64));
    }
    if (lane == 0) { redf[wv] = lmn; redf[4 + wv] = lmx; }
    __syncthreads();
    float lo = fminf(fminf(redf[0], redf[1]), fminf(redf[2], redf[3]));
    float hi = fmaxf(fmaxf(redf[4], redf[5]), fmaxf(redf[6], redf[7]));
    float range = hi - lo;
    float scale = (range > 0.f) ? (float)NBIN / range : 0.f;

#pragma unroll
    for (int k = 0; k < 4; ++k) {
        int c = tid + 256 * k;
        if (c < PC && c != targ) {
#pragma unroll
            for (int n = 0; n < 8; ++n) {
                int bin = (int)((pv[k][n] - lo) * scale);
                bin = bin < 0 ? 0 : (bin > NBIN - 1 ? NBIN - 1 : bin);
                atomicAdd(&hist[bin], 1u);
            }
        }
    }
    __syncthreads();

    // suffix scan over 1024 bins
    int b0 = tid * 4;
    unsigned h0 = hist[b0], h1 = hist[b0 + 1], h2 = hist[b0 + 2], h3 = hist[b0 + 3];
    unsigned l3 = h3, l2 = h2 + l3, l1 = h1 + l2, l0 = h0 + l1;
    unsigned T = l0;
#pragma unroll
    for (int step = 1; step < 64; step <<= 1) {
        unsigned u = __shfl_down(T, step, 64);
        if (lane + step < 64) T += u;
    }
    if (lane == 0) wtot[wv] = T;
    __syncthreads();
    unsigned tail = 0;
#pragma unroll
    for (int w2 = 0; w2 < 4; ++w2) if (w2 > wv) tail += wtot[w2];
    unsigned E = T - l0 + tail;
    {
        unsigned sfx[4] = {l0 + E, l1 + E, l2 + E, l3 + E};
        unsigned nxt[4] = {l1 + E, l2 + E, l3 + E, E};
#pragma unroll
        for (int i = 0; i < 4; ++i)
            if (sfx[i] >= NONPOS_K && nxt[i] < NONPOS_K) {
                s_bin = b0 + i;
                s_A = (int)nxt[i];
            }
    }
    __syncthreads();
    int tbin = s_bin, A = s_A;

    // collect candidates in tau's bin
#pragma unroll
    for (int k = 0; k < 4; ++k) {
        int c = tid + 256 * k;
        if (c < PC && c != targ) {
#pragma unroll
            for (int n = 0; n < 8; ++n) {
                int bin = (int)((pv[k][n] - lo) * scale);
                bin = bin < 0 ? 0 : (bin > NBIN - 1 ? NBIN - 1 : bin);
                if (bin == tbin) {
                    unsigned idx = atomicAdd(&candn, 1u);
                    if (idx < CANDMAX) cand[idx] = pv[k][n];
                }
            }
        }
    }
    __syncthreads();
    int m = (int)candn; if (m > CANDMAX) m = CANDMAX;
    int rank = NONPOS_K - A;
    for (int ci = tid; ci < m; ci += 256) {
        float val = cand[ci];
        int g = 0, e = 0;
        for (int i = 0; i < m; ++i) {
            g += cand[i] > val;
            e += cand[i] == val;
        }
        if (g < rank && rank <= g + e) { s_tau = val; s_gt = g; s_eq = e; }
    }
    __syncthreads();
    float tau = s_tau;
    int cgt = A + s_gt, ceq = s_eq;
    int rem = NONPOS_K - cgt;              // ties to include, by index order
    bool all_eq = (rem >= ceq);

    // parallel tie offsets in class-index order
    int offs[4] = {0, 0, 0, 0};
    if (!all_eq) {
        unsigned chunk_base = 0;
#pragma unroll
        for (int k = 0; k < 4; ++k) {
            int c = tid + 256 * k;
            unsigned tn = 0;
            if (c < PC && c != targ) {
#pragma unroll
                for (int n = 0; n < 8; ++n) tn += (pv[k][n] == tau) ? 1u : 0u;
            }
            unsigned inc = tn;                       // inclusive wave scan
#pragma unroll
            for (int step = 1; step < 64; step <<= 1) {
                unsigned u = __shfl_up(inc, step, 64);
                if (lane >= step) inc += u;
            }
            __syncthreads();
            if (lane == 63) wtot[wv] = inc;
            __syncthreads();
            unsigned base = 0;
#pragma unroll
            for (int w2 = 0; w2 < 4; ++w2) if (w2 < wv) base += wtot[w2];
            offs[k] = (int)(chunk_base + base + inc - tn);
            chunk_base += wtot[0] + wtot[1] + wtot[2] + wtot[3];
        }
    }

    // logits -> exp -> loss
    float psum = 0.f;
#pragma unroll
    for (int k = 0; k < 4; ++k) {
        int c = tid + 256 * k;
        if (c >= PC) continue;
        float lg = 0.f;
        if (c == targ) {
#pragma unroll
            for (int n = 0; n < 8; ++n) lg += pv[k][n];
        } else {
#pragma unroll
            for (int n = 0; n < 8; ++n) {
                float v = pv[k][n];
                bool sel = v > tau;
                if (!sel && v == tau) {
                    if (all_eq) sel = true;
                    else { sel = (offs[k] < rem); offs[k]++; }
                }
                if (sel) lg += v;
            }
        }
        float e = (lg != 0.0f) ? expf(lg) : 0.0f;
        psum += e;
        if (c == targ) s_et = e;
    }
    for (int off = 32; off; off >>= 1) psum += __shfl_down(psum, off, 64);
    if (lane == 0) redf[wv] = psum;
    __syncthreads();
    if (tid == 0) {
        float denom = 1e-8f + redf[0] + redf[1] + redf[2] + redf[3];
        atomicAdd(acc, -logf(s_et / denom + 1e-20f));
    }
}

// --------------------------------------------------------------- final ----
__global__ __launch_bounds__(256) void k_final(const float* __restrict__ esum,
                                               const float* __restrict__ diag,
                                               const float* __restrict__ acc,
                                               float* __restrict__ out) {
    __shared__ float redf[4];
    int tid = threadIdx.x, lane = tid & 63, wv = tid >> 6;
    float s = 0.f;
    for (int j = tid; j < PCN; j += 256)
        s += logf(esum[j]) - diag[j];
    for (int off = 32; off; off >>= 1) s += __shfl_down(s, off, 64);
    if (lane == 0) redf[wv] = s;
    __syncthreads();
    if (tid == 0) {
        float rg = (redf[0] + redf[1] + redf[2] + redf[3]) * (1.0f / PCN);
        float lc = acc[0] * (1.0f / PB);
        out[0] = lc + 0.3f * rg;
        out[1] = lc;
    }
}

// ---------------------------------------------------------------------------
extern "C" void kernel_launch(void* const* d_in, const int* in_sizes, int n_in,
                              void* d_out, int out_size, void* d_ws, size_t ws_size,
                              hipStream_t stream) {
    const float* x       = (const float*)d_in[0];   // (1024, 512)
    const float* proxies = (const float*)d_in[1];   // (512, 8000)
    const int*   target  = (const int*)d_in[2];     // (1024,)
    float* out = (float*)d_out;
    float* ws  = (float*)d_ws;

    // workspace layout (float offsets) — spans verified:
    //   acc    [0,        64)
    //   esum   [64,       8064)          8000 f32
    //   diag   [8064,     16064)         8000 f32
    //   xb     [16064,    278208)        1024x512 bf16 = 262144 f32
    //   cclsb  [278208,   540352)        1024x512 bf16 = 262144 f32
    //   Pt     [540352,   2588352)       8000x512 bf16 = 2048000 f32
    //   simb   [2588352,  6684352)       1024x8000 bf16 = 4096000 f32
    float*  acc   = ws;
    float*  esum  = ws + 64;
    float*  diag  = ws + 8064;
    __bf16* xb    = (__bf16*)(ws + 16064);
    __bf16* cclsb = (__bf16*)(ws + 278208);
    __bf16* Pt    = (__bf16*)(ws + 540352);
    __bf16* simb  = (__bf16*)(ws + 2588352);
    // total 6,684,352 floats = 26.7 MiB

    float* padf = (float*)cclsb + 256000;     // ccls rows 1000..1023 as f32

    k_pre<<<600, 256, 0, stream>>>(x, xb, esum, padf, acc);
    k_tpose<<<125, 256, 0, stream>>>(proxies, Pt, cclsb);

    k_gemms<<<1008, 256, 0, stream>>>(xb, Pt, cclsb, simb, esum, diag);

    k_rowloss<<<PB, 256, 0, stream>>>(simb, target, acc);
    k_final<<<1, 256, 0, stream>>>(esum, diag, acc, out);
}

// Round 11
// 145.330 us; speedup vs baseline: 1.1257x; 1.0520x over previous
//
#include <hip/hip_runtime.h>
#include <hip/hip_bf16.h>
#include <math.h>

// ProxyGML: B=1024, DIM=512, C=1000, N=8
#define PB   1024
#define PDIM 512
#define PC   1000
#define PN   8
#define PCN  8000
#define PTOPK 400
#define NONPOS_K 392
#define NBIN 1024
#define CANDMAX 1024

typedef __bf16 bf16x8 __attribute__((ext_vector_type(8)));
typedef __bf16 bf16x4 __attribute__((ext_vector_type(4)));
typedef float  f32x4  __attribute__((ext_vector_type(4)));

__device__ static inline void async_load16(const __bf16* g, __bf16* l) {
    __builtin_amdgcn_global_load_lds(
        (const __attribute__((address_space(1))) void*)g,
        (__attribute__((address_space(3))) void*)l,
        16, 0, 0);
}

// ----------------------------------------------------------------- pre ----
// b<512: x->bf16. 512..767: P column-ssq partials. 768+: zero esum/diag and
// ccls pad rows (classes 1000..1023).
__global__ __launch_bounds__(256) void k_pre(const float* __restrict__ x,
                                             const float* __restrict__ P,
                                             __bf16* __restrict__ xb,
                                             float* __restrict__ ssqp,
                                             float* __restrict__ esd,
                                             float* __restrict__ padf,
                                             float* __restrict__ acc) {
    int b = blockIdx.x, tid = threadIdx.x;
    if (b == 0 && tid < 8) acc[tid] = 0.f;
    if (b < 512) {
        int i = b * 256 + tid;
        float4 v = ((const float4*)x)[i];
        bf16x4 o;
        o[0] = (__bf16)v.x; o[1] = (__bf16)v.y; o[2] = (__bf16)v.z; o[3] = (__bf16)v.w;
        ((bf16x4*)xb)[i] = o;
    } else if (b < 768) {
        int idx = b - 512;              // 0..255
        int slice = idx & 7, jb = idx >> 3;
        int j = jb * 256 + tid;
        if (j < PCN) {
            const float* p = P + (size_t)(slice * 64) * PCN + j;
            float ss = 0.f;
#pragma unroll 8
            for (int r = 0; r < 64; ++r) {
                float v = p[(size_t)r * PCN];
                ss = fmaf(v, v, ss);
            }
            ssqp[slice * PCN + j] = ss;
        }
    } else {
        int i = (b - 768) * 256 + tid;  // 0..22271
        if (i < 16000) esd[i] = 0.f;
        else if (i < 16000 + 6144) padf[i - 16000] = 0.f;  // 24x512 bf16 pad
    }
}

// ---------------- P (512x8000) -> Pt bf16 (8000x512) + fused ccls ---------
__global__ __launch_bounds__(256) void k_tpose(const float* __restrict__ P,
                                               const float* __restrict__ ssqp,
                                               __bf16* __restrict__ Pt,
                                               __bf16* __restrict__ ccls) {
    __shared__ float t[64][65];
    __shared__ float sinv[64];
    int tid = threadIdx.x;
    int tx = tid & 63, ty = tid >> 6;
    int j0 = blockIdx.x * 64, d0 = blockIdx.y * 64;
    if (tid < 64) {
        float sq = 0.f;
#pragma unroll
        for (int p2 = 0; p2 < 8; ++p2) sq += ssqp[p2 * PCN + j0 + tid];
        sinv[tid] = 1.0f / fmaxf(sqrtf(sq), 1e-12f);
    }
#pragma unroll
    for (int r = 0; r < 16; ++r) {
        int d = d0 + ty * 16 + r;
        t[ty * 16 + r][tx] = P[(size_t)d * PCN + j0 + tx];
    }
    __syncthreads();
    float cs0 = 0.f, cs1 = 0.f;
#pragma unroll
    for (int r = 0; r < 16; ++r) {
        int jl = ty * 16 + r;
        float val = t[tx][jl] * sinv[jl];
        Pt[(size_t)(j0 + jl) * PDIM + d0 + tx] = (__bf16)val;
        if (r < 8) cs0 += val; else cs1 += val;
    }
    int c0 = (j0 >> 3) + ty * 2;           // 16 j's = 2 whole classes
    ccls[(size_t)c0 * PDIM + d0 + tx] = (__bf16)cs0;
    ccls[(size_t)(c0 + 1) * PDIM + d0 + tx] = (__bf16)cs1;
}

// ------------------------------------------------- GEMM core (macros) -----
#define GEMM_STAGE(A, Bt, Ma, Nb, m0, n0, buf, k0) {                          \
    _Pragma("unroll")                                                         \
    for (int pass = 0; pass < 2; ++pass) {                                    \
        int cc_ = pass * 256 + w * 64 + lane;                                 \
        int arow = (m0) + (cc_ >> 2); if (arow > (Ma) - 1) arow = (Ma) - 1;   \
        async_load16((A) + (size_t)arow * PDIM + (k0) + (cc_ & 3) * 8,        \
                     &As[buf][cc_ * 8]);                                      \
        int brow = (n0) + (cc_ >> 2); if (brow > (Nb) - 1) brow = (Nb) - 1;   \
        async_load16((Bt) + (size_t)brow * PDIM + (k0) + (cc_ & 3) * 8,       \
                     &Bs[buf][cc_ * 8]);                                      \
    } }

#define GEMM_CORE(A, Bt, Ma, Nb, m0, n0)                                      \
    GEMM_STAGE(A, Bt, Ma, Nb, m0, n0, 0, 0)                                   \
    for (int it = 0; it < 16; ++it) {                                         \
        int cur = it & 1;                                                     \
        __syncthreads();                                                      \
        if (it < 15) GEMM_STAGE(A, Bt, Ma, Nb, m0, n0, cur ^ 1, (it + 1) * 32)\
        bf16x8 av[4], bv[4];                                                  \
        _Pragma("unroll")                                                     \
        for (int i = 0; i < 4; ++i) {                                         \
            av[i] = *(const bf16x8*)&As[cur][(wr * 64 + i * 16 + l15) * 32 + quad * 8]; \
            bv[i] = *(const bf16x8*)&Bs[cur][(wc * 64 + i * 16 + l15) * 32 + quad * 8]; \
        }                                                                     \
        _Pragma("unroll")                                                     \
        for (int i = 0; i < 4; ++i)                                           \
            _Pragma("unroll")                                                 \
            for (int j = 0; j < 4; ++j)                                       \
                acc[i][j] = __builtin_amdgcn_mfma_f32_16x16x32_bf16(          \
                    av[i], bv[j], acc[i][j], 0, 0, 0);                        \
    }

// ---------------- merged GEMM2r (esum/diag) + GEMM1 (sim bf16) ------------
// GEMM2r blocks first (heavier epilogue -> LPT scheduling; cheap GEMM1
// blocks form the grid tail).
__global__ __launch_bounds__(256) void k_gemms(const __bf16* __restrict__ xb,
                                               const __bf16* __restrict__ Pt,
                                               const __bf16* __restrict__ ccls,
                                               __bf16* __restrict__ simb,
                                               float* __restrict__ esum,
                                               float* __restrict__ diag) {
    __shared__ __bf16 As[2][128 * 32];
    __shared__ __bf16 Bs[2][128 * 32];
    int tid = threadIdx.x;
    int w = tid >> 6, lane = tid & 63;
    int wr = w >> 1, wc = w & 1;
    int quad = lane >> 4, l15 = lane & 15;
    f32x4 acc[4][4] = {};
    int id = blockIdx.x;
    if (id < 504) {
        // GEMM2r: clog[j][c] = Pt[j]·ccls[c] -> esum[j] += sum_c exp, diag
        int n0 = (id % 8) * 128, m0 = (id / 8) * 128;
        GEMM_CORE(Pt, ccls, PCN, PB, m0, n0)
#pragma unroll
        for (int i = 0; i < 4; ++i) {
            int r0 = m0 + wr * 64 + i * 16 + quad * 4;
            float psum[4] = {0.f, 0.f, 0.f, 0.f};
#pragma unroll
            for (int j = 0; j < 4; ++j) {
                int cc = n0 + wc * 64 + j * 16 + l15;
                bool cvalid = (cc < PC);
#pragma unroll
                for (int r = 0; r < 4; ++r) {
                    float v = acc[i][j][r];
                    psum[r] += cvalid ? expf(v) : 0.f;
                    int rr = r0 + r;
                    if (cvalid && rr < PCN && cc == (rr >> 3)) diag[rr] = v;
                }
            }
#pragma unroll
            for (int off = 1; off < 16; off <<= 1)
#pragma unroll
                for (int r = 0; r < 4; ++r)
                    psum[r] += __shfl_xor(psum[r], off, 64);
            if (l15 == 0) {
#pragma unroll
                for (int r = 0; r < 4; ++r) {
                    int rr = r0 + r;
                    if (rr < PCN) atomicAdd(&esum[rr], psum[r]);
                }
            }
        }
    } else {
        // GEMM1: sim[m][j] = xb[m]·Pt[j]
        int id2 = id - 504;
        int n0 = (id2 % 63) * 128, m0 = (id2 / 63) * 128;
        GEMM_CORE(xb, Pt, PB, PCN, m0, n0)
#pragma unroll
        for (int i = 0; i < 4; ++i) {
            int r0 = m0 + wr * 64 + i * 16 + quad * 4;
#pragma unroll
            for (int j = 0; j < 4; ++j) {
                int cc = n0 + wc * 64 + j * 16 + l15;
                if (cc < PCN) {
#pragma unroll
                    for (int r = 0; r < 4; ++r)
                        simb[(size_t)(r0 + r) * PCN + cc] = (__bf16)acc[i][j][r];
                }
            }
        }
    }
}

// ------------------------------------------------------------- row loss ---
// Register-resident bf16 row; 1024-bin histogram select for tau; ties
// resolved by index order via parallel class-order prefix scan.
__global__ __launch_bounds__(256) void k_rowloss(const __bf16* __restrict__ sim,
                                                 const int* __restrict__ target,
                                                 float* __restrict__ acc) {
    __shared__ unsigned hist[NBIN];
    __shared__ float redf[8];
    __shared__ unsigned wtot[4];
    __shared__ float cand[CANDMAX];
    __shared__ unsigned candn;
    __shared__ int s_bin, s_A;
    __shared__ float s_tau;
    __shared__ int s_gt, s_eq;
    __shared__ float s_et;

    int b = blockIdx.x, tid = threadIdx.x;
    int lane = tid & 63, wv = tid >> 6;
    const bf16x8* row8 = (const bf16x8*)(sim + (size_t)b * PCN);
    int targ = target[b];

#pragma unroll
    for (int k = 0; k < 4; ++k) hist[tid + 256 * k] = 0u;
    if (tid == 0) candn = 0u;

    float pv[4][8];
    float lmn = INFINITY, lmx = -INFINITY;
#pragma unroll
    for (int k = 0; k < 4; ++k) {
        int c = tid + 256 * k;
        if (c < PC) {
            bf16x8 vv = row8[c];
#pragma unroll
            for (int n = 0; n < 8; ++n) pv[k][n] = (float)vv[n];
            if (c != targ) {
#pragma unroll
                for (int n = 0; n < 8; ++n) {
                    lmn = fminf(lmn, pv[k][n]);
                    lmx = fmaxf(lmx, pv[k][n]);
                }
            }
        } else {
#pragma unroll
            for (int n = 0; n < 8; ++n) pv[k][n] = 0.f;
        }
    }
    for (int off = 32; off; off >>= 1) {
        lmn = fminf(lmn, __shfl_down(lmn, off, 64));
        lmx = fmaxf(lmx, __shfl_down(lmx, off, 64));
    }
    if (lane == 0) { redf[wv] = lmn; redf[4 + wv] = lmx; }
    __syncthreads();
    float lo = fminf(fminf(redf[0], redf[1]), fminf(redf[2], redf[3]));
    float hi = fmaxf(fmaxf(redf[4], redf[5]), fmaxf(redf[6], redf[7]));
    float range = hi - lo;
    float scale = (range > 0.f) ? (float)NBIN / range : 0.f;

#pragma unroll
    for (int k = 0; k < 4; ++k) {
        int c = tid + 256 * k;
        if (c < PC && c != targ) {
#pragma unroll
            for (int n = 0; n < 8; ++n) {
                int bin = (int)((pv[k][n] - lo) * scale);
                bin = bin < 0 ? 0 : (bin > NBIN - 1 ? NBIN - 1 : bin);
                atomicAdd(&hist[bin], 1u);
            }
        }
    }
    __syncthreads();

    // suffix scan over 1024 bins
    int b0 = tid * 4;
    unsigned h0 = hist[b0], h1 = hist[b0 + 1], h2 = hist[b0 + 2], h3 = hist[b0 + 3];
    unsigned l3 = h3, l2 = h2 + l3, l1 = h1 + l2, l0 = h0 + l1;
    unsigned T = l0;
#pragma unroll
    for (int step = 1; step < 64; step <<= 1) {
        unsigned u = __shfl_down(T, step, 64);
        if (lane + step < 64) T += u;
    }
    if (lane == 0) wtot[wv] = T;
    __syncthreads();
    unsigned tail = 0;
#pragma unroll
    for (int w2 = 0; w2 < 4; ++w2) if (w2 > wv) tail += wtot[w2];
    unsigned E = T - l0 + tail;
    {
        unsigned sfx[4] = {l0 + E, l1 + E, l2 + E, l3 + E};
        unsigned nxt[4] = {l1 + E, l2 + E, l3 + E, E};
#pragma unroll
        for (int i = 0; i < 4; ++i)
            if (sfx[i] >= NONPOS_K && nxt[i] < NONPOS_K) {
                s_bin = b0 + i;
                s_A = (int)nxt[i];
            }
    }
    __syncthreads();
    int tbin = s_bin, A = s_A;

    // collect candidates in tau's bin
#pragma unroll
    for (int k = 0; k < 4; ++k) {
        int c = tid + 256 * k;
        if (c < PC && c != targ) {
#pragma unroll
            for (int n = 0; n < 8; ++n) {
                int bin = (int)((pv[k][n] - lo) * scale);
                bin = bin < 0 ? 0 : (bin > NBIN - 1 ? NBIN - 1 : bin);
                if (bin == tbin) {
                    unsigned idx = atomicAdd(&candn, 1u);
                    if (idx < CANDMAX) cand[idx] = pv[k][n];
                }
            }
        }
    }
    __syncthreads();
    int m = (int)candn; if (m > CANDMAX) m = CANDMAX;
    int rank = NONPOS_K - A;
    for (int ci = tid; ci < m; ci += 256) {
        float val = cand[ci];
        int g = 0, e = 0;
        for (int i = 0; i < m; ++i) {
            g += cand[i] > val;
            e += cand[i] == val;
        }
        if (g < rank && rank <= g + e) { s_tau = val; s_gt = g; s_eq = e; }
    }
    __syncthreads();
    float tau = s_tau;
    int cgt = A + s_gt, ceq = s_eq;
    int rem = NONPOS_K - cgt;              // ties to include, by index order
    bool all_eq = (rem >= ceq);

    // parallel tie offsets in class-index order
    int offs[4] = {0, 0, 0, 0};
    if (!all_eq) {
        unsigned chunk_base = 0;
#pragma unroll
        for (int k = 0; k < 4; ++k) {
            int c = tid + 256 * k;
            unsigned tn = 0;
            if (c < PC && c != targ) {
#pragma unroll
                for (int n = 0; n < 8; ++n) tn += (pv[k][n] == tau) ? 1u : 0u;
            }
            unsigned inc = tn;                       // inclusive wave scan
#pragma unroll
            for (int step = 1; step < 64; step <<= 1) {
                unsigned u = __shfl_up(inc, step, 64);
                if (lane >= step) inc += u;
            }
            __syncthreads();
            if (lane == 63) wtot[wv] = inc;
            __syncthreads();
            unsigned base = 0;
#pragma unroll
            for (int w2 = 0; w2 < 4; ++w2) if (w2 < wv) base += wtot[w2];
            offs[k] = (int)(chunk_base + base + inc - tn);
            chunk_base += wtot[0] + wtot[1] + wtot[2] + wtot[3];
        }
    }

    // logits -> exp -> loss
    float psum = 0.f;
#pragma unroll
    for (int k = 0; k < 4; ++k) {
        int c = tid + 256 * k;
        if (c >= PC) continue;
        float lg = 0.f;
        if (c == targ) {
#pragma unroll
            for (int n = 0; n < 8; ++n) lg += pv[k][n];
        } else {
#pragma unroll
            for (int n = 0; n < 8; ++n) {
                float v = pv[k][n];
                bool sel = v > tau;
                if (!sel && v == tau) {
                    if (all_eq) sel = true;
                    else { sel = (offs[k] < rem); offs[k]++; }
                }
                if (sel) lg += v;
            }
        }
        float e = (lg != 0.0f) ? expf(lg) : 0.0f;
        psum += e;
        if (c == targ) s_et = e;
    }
    for (int off = 32; off; off >>= 1) psum += __shfl_down(psum, off, 64);
    if (lane == 0) redf[wv] = psum;
    __syncthreads();
    if (tid == 0) {
        float denom = 1e-8f + redf[0] + redf[1] + redf[2] + redf[3];
        atomicAdd(acc, -logf(s_et / denom + 1e-20f));
    }
}

// --------------------------------------------------------------- final ----
__global__ __launch_bounds__(256) void k_final(const float* __restrict__ esum,
                                               const float* __restrict__ diag,
                                               const float* __restrict__ acc,
                                               float* __restrict__ out) {
    __shared__ float redf[4];
    int tid = threadIdx.x, lane = tid & 63, wv = tid >> 6;
    float s = 0.f;
    for (int j = tid; j < PCN; j += 256)
        s += logf(esum[j]) - diag[j];
    for (int off = 32; off; off >>= 1) s += __shfl_down(s, off, 64);
    if (lane == 0) redf[wv] = s;
    __syncthreads();
    if (tid == 0) {
        float rg = (redf[0] + redf[1] + redf[2] + redf[3]) * (1.0f / PCN);
        float lc = acc[0] * (1.0f / PB);
        out[0] = lc + 0.3f * rg;
        out[1] = lc;
    }
}

// ---------------------------------------------------------------------------
extern "C" void kernel_launch(void* const* d_in, const int* in_sizes, int n_in,
                              void* d_out, int out_size, void* d_ws, size_t ws_size,
                              hipStream_t stream) {
    const float* x       = (const float*)d_in[0];   // (1024, 512)
    const float* proxies = (const float*)d_in[1];   // (512, 8000)
    const int*   target  = (const int*)d_in[2];     // (1024,)
    float* out = (float*)d_out;
    float* ws  = (float*)d_ws;

    // workspace layout (float offsets) — spans verified:
    //   acc    [0,      64)
    //   ssqp   [64,     64064)     8x8000 f32
    //   esum   [64064,  72064)     8000 f32
    //   diag   [72064,  80064)     8000 f32
    //   xb     [80064,  342208)    1024x512 bf16 = 262144 f32
    //   cclsb  [342208, 604352)    1024x512 bf16 = 262144 f32
    //   Pt     [604352, 2652352)   8000x512 bf16 = 2048000 f32
    //   simb   [2652352,6748352)   1024x8000 bf16 = 4096000 f32
    float*  acc   = ws;
    float*  ssqp  = ws + 64;
    float*  esum  = ws + 64064;
    float*  diag  = ws + 72064;
    __bf16* xb    = (__bf16*)(ws + 80064);
    __bf16* cclsb = (__bf16*)(ws + 342208);
    __bf16* Pt    = (__bf16*)(ws + 604352);
    __bf16* simb  = (__bf16*)(ws + 2652352);
    // total 6,748,352 floats = 27.0 MiB

    float* padf = (float*)cclsb + 256000;     // ccls rows 1000..1023 as f32

    k_pre<<<856, 256, 0, stream>>>(x, proxies, xb, ssqp, esum, padf, acc);
    k_tpose<<<dim3(125, 8), 256, 0, stream>>>(proxies, ssqp, Pt, cclsb);

    k_gemms<<<1008, 256, 0, stream>>>(xb, Pt, cclsb, simb, esum, diag);

    k_rowloss<<<PB, 256, 0, stream>>>(simb, target, acc);
    k_final<<<1, 256, 0, stream>>>(esum, diag, acc, out);
}

// Round 12
// 139.875 us; speedup vs baseline: 1.1696x; 1.0390x over previous
//
#include <hip/hip_runtime.h>
#include <hip/hip_bf16.h>
#include <math.h>

// ProxyGML: B=1024, DIM=512, C=1000, N=8
#define PB   1024
#define PDIM 512
#define PC   1000
#define PN   8
#define PCN  8000
#define PTOPK 400
#define NONPOS_K 392
#define NBIN 1024
#define CANDMAX 1024

typedef __bf16 bf16x8 __attribute__((ext_vector_type(8)));
typedef __bf16 bf16x4 __attribute__((ext_vector_type(4)));
typedef float  f32x4  __attribute__((ext_vector_type(4)));

__device__ static inline void async_load16(const __bf16* g, __bf16* l) {
    __builtin_amdgcn_global_load_lds(
        (const __attribute__((address_space(1))) void*)g,
        (__attribute__((address_space(3))) void*)l,
        16, 0, 0);
}

// ----------------------------------------------------------------- pre ----
// b<512: x->bf16. 512..767: P column-ssq partials. 768+: zero esum/diag and
// ccls pad rows (classes 1000..1023).
__global__ __launch_bounds__(256) void k_pre(const float* __restrict__ x,
                                             const float* __restrict__ P,
                                             __bf16* __restrict__ xb,
                                             float* __restrict__ ssqp,
                                             float* __restrict__ esd,
                                             float* __restrict__ padf,
                                             float* __restrict__ acc) {
    int b = blockIdx.x, tid = threadIdx.x;
    if (b == 0 && tid < 8) acc[tid] = 0.f;
    if (b < 512) {
        int i = b * 256 + tid;
        float4 v = ((const float4*)x)[i];
        bf16x4 o;
        o[0] = (__bf16)v.x; o[1] = (__bf16)v.y; o[2] = (__bf16)v.z; o[3] = (__bf16)v.w;
        ((bf16x4*)xb)[i] = o;
    } else if (b < 768) {
        int idx = b - 512;              // 0..255
        int slice = idx & 7, jb = idx >> 3;
        int j = jb * 256 + tid;
        if (j < PCN) {
            const float* p = P + (size_t)(slice * 64) * PCN + j;
            float ss = 0.f;
#pragma unroll 8
            for (int r = 0; r < 64; ++r) {
                float v = p[(size_t)r * PCN];
                ss = fmaf(v, v, ss);
            }
            ssqp[slice * PCN + j] = ss;
        }
    } else {
        int i = (b - 768) * 256 + tid;  // 0..22271
        if (i < 16000) esd[i] = 0.f;
        else if (i < 16000 + 6144) padf[i - 16000] = 0.f;  // 24x512 bf16 pad
    }
}

// ---------------- P (512x8000) -> Pt bf16 (8000x512) + fused ccls ---------
__global__ __launch_bounds__(256) void k_tpose(const float* __restrict__ P,
                                               const float* __restrict__ ssqp,
                                               __bf16* __restrict__ Pt,
                                               __bf16* __restrict__ ccls) {
    __shared__ float t[64][65];
    __shared__ float sinv[64];
    int tid = threadIdx.x;
    int tx = tid & 63, ty = tid >> 6;
    int j0 = blockIdx.x * 64, d0 = blockIdx.y * 64;
    if (tid < 64) {
        float sq = 0.f;
#pragma unroll
        for (int p2 = 0; p2 < 8; ++p2) sq += ssqp[p2 * PCN + j0 + tid];
        sinv[tid] = 1.0f / fmaxf(sqrtf(sq), 1e-12f);
    }
#pragma unroll
    for (int r = 0; r < 16; ++r) {
        int d = d0 + ty * 16 + r;
        t[ty * 16 + r][tx] = P[(size_t)d * PCN + j0 + tx];
    }
    __syncthreads();
    float cs0 = 0.f, cs1 = 0.f;
#pragma unroll
    for (int r = 0; r < 16; ++r) {
        int jl = ty * 16 + r;
        float val = t[tx][jl] * sinv[jl];
        Pt[(size_t)(j0 + jl) * PDIM + d0 + tx] = (__bf16)val;
        if (r < 8) cs0 += val; else cs1 += val;
    }
    int c0 = (j0 >> 3) + ty * 2;           // 16 j's = 2 whole classes
    ccls[(size_t)c0 * PDIM + d0 + tx] = (__bf16)cs0;
    ccls[(size_t)(c0 + 1) * PDIM + d0 + tx] = (__bf16)cs1;
}

// -------------- pair-fused GEMM: block (jt,t) shares the Pt tile ----------
// sim[m=t-tile][j=jt-tile] = xb · Pt^T   and
// clog[j=jt-tile][c=t-tile] = Pt · ccls^T -> esum/diag epilogue.
// 3 tiles staged per K-step, 32 MFMA per barrier.
__global__ __launch_bounds__(256, 2) void k_gemms(const __bf16* __restrict__ xb,
                                                  const __bf16* __restrict__ Pt,
                                                  const __bf16* __restrict__ ccls,
                                                  __bf16* __restrict__ simb,
                                                  float* __restrict__ esum,
                                                  float* __restrict__ diag) {
    __shared__ __bf16 Xs[2][128 * 32];
    __shared__ __bf16 Ps[2][128 * 32];
    __shared__ __bf16 Cs[2][128 * 32];
    int tid = threadIdx.x;
    int w = tid >> 6, lane = tid & 63;
    int wr = w >> 1, wc = w & 1;
    int quad = lane >> 4, l15 = lane & 15;
    int id = blockIdx.x;
    int jt = id >> 3, t = id & 7;          // 63 x 8
    int m0 = t * 128;                      // xb rows / ccls rows (exact)
    int n0 = jt * 128;                     // Pt rows (guard 8000)

    f32x4 accS[4][4] = {};                 // sim
    f32x4 accC[4][4] = {};                 // clog

#define STAGE3(buf, k0) {                                                     \
    _Pragma("unroll")                                                         \
    for (int pass = 0; pass < 2; ++pass) {                                    \
        int cc_ = pass * 256 + w * 64 + lane;                                 \
        int row_ = cc_ >> 2, ko_ = (cc_ & 3) * 8;                             \
        async_load16(xb + (size_t)(m0 + row_) * PDIM + (k0) + ko_,            \
                     &Xs[buf][cc_ * 8]);                                      \
        int prow = n0 + row_; if (prow > PCN - 1) prow = PCN - 1;             \
        async_load16(Pt + (size_t)prow * PDIM + (k0) + ko_,                   \
                     &Ps[buf][cc_ * 8]);                                      \
        async_load16(ccls + (size_t)(m0 + row_) * PDIM + (k0) + ko_,          \
                     &Cs[buf][cc_ * 8]);                                      \
    } }

    STAGE3(0, 0)
    for (int it = 0; it < 16; ++it) {
        int cur = it & 1;
        __syncthreads();
        if (it < 15) STAGE3(cur ^ 1, (it + 1) * 32)
        bf16x8 xa[4], pb[4], pa[4], cb[4];
#pragma unroll
        for (int i = 0; i < 4; ++i) {
            xa[i] = *(const bf16x8*)&Xs[cur][(wr * 64 + i * 16 + l15) * 32 + quad * 8];
            pb[i] = *(const bf16x8*)&Ps[cur][(wc * 64 + i * 16 + l15) * 32 + quad * 8];
            pa[i] = *(const bf16x8*)&Ps[cur][(wr * 64 + i * 16 + l15) * 32 + quad * 8];
            cb[i] = *(const bf16x8*)&Cs[cur][(wc * 64 + i * 16 + l15) * 32 + quad * 8];
        }
#pragma unroll
        for (int i = 0; i < 4; ++i)
#pragma unroll
            for (int j = 0; j < 4; ++j) {
                accS[i][j] = __builtin_amdgcn_mfma_f32_16x16x32_bf16(
                    xa[i], pb[j], accS[i][j], 0, 0, 0);
                accC[i][j] = __builtin_amdgcn_mfma_f32_16x16x32_bf16(
                    pa[i], cb[j], accC[i][j], 0, 0, 0);
            }
    }
#undef STAGE3

    // epilogue 1: sim store (rows m0+.., cols n0+.. over CN)
#pragma unroll
    for (int i = 0; i < 4; ++i) {
        int r0 = m0 + wr * 64 + i * 16 + quad * 4;
#pragma unroll
        for (int j = 0; j < 4; ++j) {
            int cc = n0 + wc * 64 + j * 16 + l15;
            if (cc < PCN) {
#pragma unroll
                for (int r = 0; r < 4; ++r)
                    simb[(size_t)(r0 + r) * PCN + cc] = (__bf16)accS[i][j][r];
            }
        }
    }
    // epilogue 2: clog -> esum/diag (rows n0+.. over CN, cols m0+.. over C)
#pragma unroll
    for (int i = 0; i < 4; ++i) {
        int r0 = n0 + wr * 64 + i * 16 + quad * 4;
        float psum[4] = {0.f, 0.f, 0.f, 0.f};
#pragma unroll
        for (int j = 0; j < 4; ++j) {
            int cc = m0 + wc * 64 + j * 16 + l15;
            bool cvalid = (cc < PC);
#pragma unroll
            for (int r = 0; r < 4; ++r) {
                float v = accC[i][j][r];
                psum[r] += cvalid ? expf(v) : 0.f;
                int rr = r0 + r;
                if (cvalid && rr < PCN && cc == (rr >> 3)) diag[rr] = v;
            }
        }
#pragma unroll
        for (int off = 1; off < 16; off <<= 1)
#pragma unroll
            for (int r = 0; r < 4; ++r)
                psum[r] += __shfl_xor(psum[r], off, 64);
        if (l15 == 0) {
#pragma unroll
            for (int r = 0; r < 4; ++r) {
                int rr = r0 + r;
                if (rr < PCN) atomicAdd(&esum[rr], psum[r]);
            }
        }
    }
}

// ------------------------------------------------------------- row loss ---
// Register-resident bf16 row; 1024-bin histogram select for tau; ties
// resolved by index order via parallel class-order prefix scan.
__global__ __launch_bounds__(256) void k_rowloss(const __bf16* __restrict__ sim,
                                                 const int* __restrict__ target,
                                                 float* __restrict__ acc) {
    __shared__ unsigned hist[NBIN];
    __shared__ float redf[8];
    __shared__ unsigned wtot[4];
    __shared__ float cand[CANDMAX];
    __shared__ unsigned candn;
    __shared__ int s_bin, s_A;
    __shared__ float s_tau;
    __shared__ int s_gt, s_eq;
    __shared__ float s_et;

    int b = blockIdx.x, tid = threadIdx.x;
    int lane = tid & 63, wv = tid >> 6;
    const bf16x8* row8 = (const bf16x8*)(sim + (size_t)b * PCN);
    int targ = target[b];

#pragma unroll
    for (int k = 0; k < 4; ++k) hist[tid + 256 * k] = 0u;
    if (tid == 0) candn = 0u;

    float pv[4][8];
    float lmn = INFINITY, lmx = -INFINITY;
#pragma unroll
    for (int k = 0; k < 4; ++k) {
        int c = tid + 256 * k;
        if (c < PC) {
            bf16x8 vv = row8[c];
#pragma unroll
            for (int n = 0; n < 8; ++n) pv[k][n] = (float)vv[n];
            if (c != targ) {
#pragma unroll
                for (int n = 0; n < 8; ++n) {
                    lmn = fminf(lmn, pv[k][n]);
                    lmx = fmaxf(lmx, pv[k][n]);
                }
            }
        } else {
#pragma unroll
            for (int n = 0; n < 8; ++n) pv[k][n] = 0.f;
        }
    }
    for (int off = 32; off; off >>= 1) {
        lmn = fminf(lmn, __shfl_down(lmn, off, 64));
        lmx = fmaxf(lmx, __shfl_down(lmx, off, 64));
    }
    if (lane == 0) { redf[wv] = lmn; redf[4 + wv] = lmx; }
    __syncthreads();
    float lo = fminf(fminf(redf[0], redf[1]), fminf(redf[2], redf[3]));
    float hi = fmaxf(fmaxf(redf[4], redf[5]), fmaxf(redf[6], redf[7]));
    float range = hi - lo;
    float scale = (range > 0.f) ? (float)NBIN / range : 0.f;

#pragma unroll
    for (int k = 0; k < 4; ++k) {
        int c = tid + 256 * k;
        if (c < PC && c != targ) {
#pragma unroll
            for (int n = 0; n < 8; ++n) {
                int bin = (int)((pv[k][n] - lo) * scale);
                bin = bin < 0 ? 0 : (bin > NBIN - 1 ? NBIN - 1 : bin);
                atomicAdd(&hist[bin], 1u);
            }
        }
    }
    __syncthreads();

    // suffix scan over 1024 bins
    int b0 = tid * 4;
    unsigned h0 = hist[b0], h1 = hist[b0 + 1], h2 = hist[b0 + 2], h3 = hist[b0 + 3];
    unsigned l3 = h3, l2 = h2 + l3, l1 = h1 + l2, l0 = h0 + l1;
    unsigned T = l0;
#pragma unroll
    for (int step = 1; step < 64; step <<= 1) {
        unsigned u = __shfl_down(T, step, 64);
        if (lane + step < 64) T += u;
    }
    if (lane == 0) wtot[wv] = T;
    __syncthreads();
    unsigned tail = 0;
#pragma unroll
    for (int w2 = 0; w2 < 4; ++w2) if (w2 > wv) tail += wtot[w2];
    unsigned E = T - l0 + tail;
    {
        unsigned sfx[4] = {l0 + E, l1 + E, l2 + E, l3 + E};
        unsigned nxt[4] = {l1 + E, l2 + E, l3 + E, E};
#pragma unroll
        for (int i = 0; i < 4; ++i)
            if (sfx[i] >= NONPOS_K && nxt[i] < NONPOS_K) {
                s_bin = b0 + i;
                s_A = (int)nxt[i];
            }
    }
    __syncthreads();
    int tbin = s_bin, A = s_A;

    // collect candidates in tau's bin
#pragma unroll
    for (int k = 0; k < 4; ++k) {
        int c = tid + 256 * k;
        if (c < PC && c != targ) {
#pragma unroll
            for (int n = 0; n < 8; ++n) {
                int bin = (int)((pv[k][n] - lo) * scale);
                bin = bin < 0 ? 0 : (bin > NBIN - 1 ? NBIN - 1 : bin);
                if (bin == tbin) {
                    unsigned idx = atomicAdd(&candn, 1u);
                    if (idx < CANDMAX) cand[idx] = pv[k][n];
                }
            }
        }
    }
    __syncthreads();
    int m = (int)candn; if (m > CANDMAX) m = CANDMAX;
    int rank = NONPOS_K - A;
    for (int ci = tid; ci < m; ci += 256) {
        float val = cand[ci];
        int g = 0, e = 0;
        for (int i = 0; i < m; ++i) {
            g += cand[i] > val;
            e += cand[i] == val;
        }
        if (g < rank && rank <= g + e) { s_tau = val; s_gt = g; s_eq = e; }
    }
    __syncthreads();
    float tau = s_tau;
    int cgt = A + s_gt, ceq = s_eq;
    int rem = NONPOS_K - cgt;              // ties to include, by index order
    bool all_eq = (rem >= ceq);

    // parallel tie offsets in class-index order
    int offs[4] = {0, 0, 0, 0};
    if (!all_eq) {
        unsigned chunk_base = 0;
#pragma unroll
        for (int k = 0; k < 4; ++k) {
            int c = tid + 256 * k;
            unsigned tn = 0;
            if (c < PC && c != targ) {
#pragma unroll
                for (int n = 0; n < 8; ++n) tn += (pv[k][n] == tau) ? 1u : 0u;
            }
            unsigned inc = tn;                       // inclusive wave scan
#pragma unroll
            for (int step = 1; step < 64; step <<= 1) {
                unsigned u = __shfl_up(inc, step, 64);
                if (lane >= step) inc += u;
            }
            __syncthreads();
            if (lane == 63) wtot[wv] = inc;
            __syncthreads();
            unsigned base = 0;
#pragma unroll
            for (int w2 = 0; w2 < 4; ++w2) if (w2 < wv) base += wtot[w2];
            offs[k] = (int)(chunk_base + base + inc - tn);
            chunk_base += wtot[0] + wtot[1] + wtot[2] + wtot[3];
        }
    }

    // logits -> exp -> loss
    float psum = 0.f;
#pragma unroll
    for (int k = 0; k < 4; ++k) {
        int c = tid + 256 * k;
        if (c >= PC) continue;
        float lg = 0.f;
        if (c == targ) {
#pragma unroll
            for (int n = 0; n < 8; ++n) lg += pv[k][n];
        } else {
#pragma unroll
            for (int n = 0; n < 8; ++n) {
                float v = pv[k][n];
                bool sel = v > tau;
                if (!sel && v == tau) {
                    if (all_eq) sel = true;
                    else { sel = (offs[k] < rem); offs[k]++; }
                }
                if (sel) lg += v;
            }
        }
        float e = (lg != 0.0f) ? expf(lg) : 0.0f;
        psum += e;
        if (c == targ) s_et = e;
    }
    for (int off = 32; off; off >>= 1) psum += __shfl_down(psum, off, 64);
    if (lane == 0) redf[wv] = psum;
    __syncthreads();
    if (tid == 0) {
        float denom = 1e-8f + redf[0] + redf[1] + redf[2] + redf[3];
        atomicAdd(acc, -logf(s_et / denom + 1e-20f));
    }
}

// --------------------------------------------------------------- final ----
__global__ __launch_bounds__(256) void k_final(const float* __restrict__ esum,
                                               const float* __restrict__ diag,
                                               const float* __restrict__ acc,
                                               float* __restrict__ out) {
    __shared__ float redf[4];
    int tid = threadIdx.x, lane = tid & 63, wv = tid >> 6;
    float s = 0.f;
    for (int j = tid; j < PCN; j += 256)
        s += logf(esum[j]) - diag[j];
    for (int off = 32; off; off >>= 1) s += __shfl_down(s, off, 64);
    if (lane == 0) redf[wv] = s;
    __syncthreads();
    if (tid == 0) {
        float rg = (redf[0] + redf[1] + redf[2] + redf[3]) * (1.0f / PCN);
        float lc = acc[0] * (1.0f / PB);
        out[0] = lc + 0.3f * rg;
        out[1] = lc;
    }
}

// ---------------------------------------------------------------------------
extern "C" void kernel_launch(void* const* d_in, const int* in_sizes, int n_in,
                              void* d_out, int out_size, void* d_ws, size_t ws_size,
                              hipStream_t stream) {
    const float* x       = (const float*)d_in[0];   // (1024, 512)
    const float* proxies = (const float*)d_in[1];   // (512, 8000)
    const int*   target  = (const int*)d_in[2];     // (1024,)
    float* out = (float*)d_out;
    float* ws  = (float*)d_ws;

    // workspace layout (float offsets) — spans verified:
    //   acc    [0,      64)
    //   ssqp   [64,     64064)     8x8000 f32
    //   esum   [64064,  72064)     8000 f32
    //   diag   [72064,  80064)     8000 f32
    //   xb     [80064,  342208)    1024x512 bf16 = 262144 f32
    //   cclsb  [342208, 604352)    1024x512 bf16 = 262144 f32
    //   Pt     [604352, 2652352)   8000x512 bf16 = 2048000 f32
    //   simb   [2652352,6748352)   1024x8000 bf16 = 4096000 f32
    float*  acc   = ws;
    float*  ssqp  = ws + 64;
    float*  esum  = ws + 64064;
    float*  diag  = ws + 72064;
    __bf16* xb    = (__bf16*)(ws + 80064);
    __bf16* cclsb = (__bf16*)(ws + 342208);
    __bf16* Pt    = (__bf16*)(ws + 604352);
    __bf16* simb  = (__bf16*)(ws + 2652352);
    // total 6,748,352 floats = 27.0 MiB

    float* padf = (float*)cclsb + 256000;     // ccls rows 1000..1023 as f32

    k_pre<<<856, 256, 0, stream>>>(x, proxies, xb, ssqp, esum, padf, acc);
    k_tpose<<<dim3(125, 8), 256, 0, stream>>>(proxies, ssqp, Pt, cclsb);

    k_gemms<<<504, 256, 0, stream>>>(xb, Pt, cclsb, simb, esum, diag);

    k_rowloss<<<PB, 256, 0, stream>>>(simb, target, acc);
    k_final<<<1, 256, 0, stream>>>(esum, diag, acc, out);
}